// Round 1
// 1064.310 us; speedup vs baseline: 1.0901x; 1.0901x over previous
//
#include <hip/hip_runtime.h>
#include <hip/hip_bf16.h>
#include <math.h>

#define HW 4096
#define NB 8
#define NT 16

typedef unsigned short u16;
typedef __attribute__((ext_vector_type(8))) short bf16x8;
typedef __attribute__((ext_vector_type(4))) float f32x4;

__device__ __forceinline__ float sigmoid_f(float x) {
  return 1.f / (1.f + __expf(-x));
}
__device__ __forceinline__ float tanh_f(float x) {
  float ax = fabsf(x);
  float e = __expf(2.f * ax);
  float t = 1.f - 2.f / (e + 1.f);
  return copysignf(t, x);
}
__device__ __forceinline__ u16 f2b(float v) {
  __hip_bfloat16 h = __float2bfloat16(v);
  return *(u16*)&h;
}

// ---- weight transform: w[256][CIN][3][3] f32 -> wtB[chunk][tap][gate][32ci] bf16
__global__ void transform_wB(const float* __restrict__ w, u16* __restrict__ wtB,
                             int CIN, int cinbase, int nch) {
  int idx = blockIdx.x * 256 + threadIdx.x;
  int total = nch * 9 * 256 * 32;
  if (idx >= total) return;
  int ci32 = idx & 31;
  int rest = idx >> 5;
  int gate = rest & 255;
  rest >>= 8;
  int tap = rest % 9;
  int chunk = rest / 9;
  int cin = cinbase + chunk * 32 + ci32;
  wtB[idx] = f2b(w[((size_t)gate * CIN + cin) * 9 + tap]);
}

// ---- layer0 xin-part weights: wtA[gate][32k] bf16, k = ci*9+tap (ci<3), pad 0
__global__ void transform_wA(const float* __restrict__ w0, u16* __restrict__ wtA) {
  int idx = blockIdx.x * 256 + threadIdx.x;  // 8192
  if (idx >= 8192) return;
  int k = idx & 31, gate = idx >> 5;
  u16 v = 0;
  if (k < 27) {
    int ci = (k >= 18) + (k >= 9);
    int tap = k - ci * 9;
    v = f2b(w0[((size_t)gate * 67 + ci) * 9 + tap]);
  }
  wtA[idx] = v;
}

// ---- attention reduce: per (b,t,c) avg & max over HW ----
__global__ void att_reduce(const float* __restrict__ x, float* __restrict__ avg,
                           float* __restrict__ mx) {
  int btc = blockIdx.x;  // 384
  const float* p = x + (size_t)btc * HW;
  float s = 0.f, m = -INFINITY;
  for (int i = threadIdx.x; i < HW; i += 256) {
    float v = p[i];
    s += v;
    m = fmaxf(m, v);
  }
  #pragma unroll
  for (int off = 32; off; off >>= 1) {
    s += __shfl_down(s, off, 64);
    m = fmaxf(m, __shfl_down(m, off, 64));
  }
  __shared__ float ss[4], sm[4];
  int wid = threadIdx.x >> 6, lane = threadIdx.x & 63;
  if (lane == 0) { ss[wid] = s; sm[wid] = m; }
  __syncthreads();
  if (threadIdx.x == 0) {
    avg[btc] = (ss[0] + ss[1] + ss[2] + ss[3]) * (1.f / 4096.f);
    mx[btc]  = fmaxf(fmaxf(sm[0], sm[1]), fmaxf(sm[2], sm[3]));
  }
}

// ---- attention apply -> xin_t[bt][pix][4ci] bf16 (channel-last, slot3 = 0) ----
__global__ void att_apply(const float* __restrict__ x, const float* __restrict__ avg,
                          const float* __restrict__ mx, const float* __restrict__ w1,
                          const float* __restrict__ w2, u16* __restrict__ xin_t) {
  size_t i = (size_t)blockIdx.x * 256 + threadIdx.x;  // 1,572,864 = (bt, c, pix)
  int pix = (int)(i & 4095);
  int c   = (int)((i >> 12) % 3);
  int bt  = (int)(i / (3 * HW));
  const float* a = avg + bt * 3;
  const float* m = mx + bt * 3;
  float ra = fmaxf(0.f, w1[0] * a[0] + w1[1] * a[1] + w1[2] * a[2]);
  float rm = fmaxf(0.f, w1[0] * m[0] + w1[1] * m[1] + w1[2] * m[2]);
  float sc = sigmoid_f(w2[c] * (ra + rm));
  xin_t[((size_t)bt * HW + pix) * 4 + c] = f2b(x[i] * sc);
}

// ---- fused implicit-GEMM conv + LSTM pointwise (MFMA bf16), pipelined ----
// block = 1 image row (64 px) x 256 gates, 4 waves; wave w: N-tiles {w,w+4,w+8,w+12}
// h sources laid out [b][2 ch-halves][4096 px][32 ch] bf16 (chunk stride 131072 elems)
// Pipeline per chunk: issue next-chunk global loads early (T14 issue-early), B-frag
// ring of 3 tap-slots prefetched 3 taps ahead (covers L2 latency), av double-buffer
// (next tap's ds_reads under current MFMAs), ds_write of next chunk at tap 5 into
// the other LDS buffer, ONE barrier per chunk.
#define ST_LOAD1(DST, IDX)                                                   \
  {                                                                          \
    int _site = (IDX) >> 2, _sub = (IDX) & 3;                                \
    int _r = _site / 66, _cc = _site - _r * 66;                              \
    int _gr = r0 - 1 + _r, _gc = _cc - 1;                                    \
    DST = make_uint4(0u, 0u, 0u, 0u);                                        \
    if ((unsigned)_gr < 64u && (unsigned)_gc < 64u)                          \
      DST = *(const uint4*)(sp + (size_t)(_gr * 64 + _gc) * 32 + _sub * 8);  \
  }

#define SP_SET(CG)                                                           \
  sp = ((CG) < s0_ch)                                                        \
     ? s0 + (size_t)b * s0_bs + (size_t)(CG) * 131072                        \
     : s1 + (size_t)b * s1_bs + (size_t)((CG) - s0_ch) * 131072;

#define STAGE_LOADS()                                                        \
  { ST_LOAD1(st0, tid) ST_LOAD1(st1, tid + 256) ST_LOAD1(st2, tid + 512)     \
    if (tid < 24) ST_LOAD1(st3, tid + 768) }

#define STAGE_WRITE(BUFP)                                                    \
  { uint4* _d = (uint4*)(BUFP);                                              \
    _d[tid] = st0; _d[tid + 256] = st1; _d[tid + 512] = st2;                 \
    if (tid < 24) _d[tid + 768] = st3; }

#define BISSUE(S, BP, TP)                                                    \
  { _Pragma("unroll")                                                        \
    for (int _g = 0; _g < 4; ++_g)                                           \
      bq[S][_g] = *(const bf16x8*)((BP) + (TP) * 8192 + _g * 2048); }

__global__ __launch_bounds__(256, 2) void conv_step(
    const u16* __restrict__ a0, long a0_bs,          // layer0 xin_t (or null)
    const u16* __restrict__ wtA,
    const u16* __restrict__ s0, long s0_bs, int s0_ch,
    const u16* __restrict__ s1, long s1_bs, int s1_ch,
    const u16* __restrict__ wtB,
    const float* __restrict__ bias,
    float* __restrict__ c_t,                          // [b][4096][64] f32
    u16* __restrict__ h_t,                            // [b][2][4096][32] bf16
    float* __restrict__ out_f32, long out_bs)         // [b][.][gate-ch][4096] f32 or null
{
  __shared__ __align__(16) u16 smem[2][6336];         // 2 x 12,672 B double buffer
  const int r0 = blockIdx.x, b = blockIdx.y;
  const int tid = threadIdx.x;
  const int w = tid >> 6, lane = tid & 63;
  const int n = lane & 15, q = lane >> 4;
  const int abase = n * 32 + q * 8;
  const int ntot = s0_ch + s1_ch;

  f32x4 acc[4][4];
  #pragma unroll
  for (int mt = 0; mt < 4; ++mt)
    #pragma unroll
    for (int gt = 0; gt < 4; ++gt)
      acc[mt][gt] = (f32x4){0.f, 0.f, 0.f, 0.f};

  const u16* bp = wtB + (size_t)(w * 16 + n) * 32 + q * 8;
  bf16x8 bq[3][4];
  bf16x8 av[2][4];
  uint4 st0 = make_uint4(0u, 0u, 0u, 0u), st1 = st0, st2 = st0, st3 = st0;
  const u16* sp;

  // issue chunk-0 stage loads first (oldest vmem, drains first)
  SP_SET(0);
  STAGE_LOADS();

  int cur;
  if (a0) {
    // ---- layer-0 xin part: one K=32 im2col tile into buf0 ----
    const u16* ap = a0 + (size_t)b * a0_bs;
    for (int idx = tid; idx < 2048; idx += 256) {
      int k = idx & 31, px = idx >> 5;
      u16 v = 0;
      if (k < 27) {
        int ci = (k >= 18) + (k >= 9);
        int tap = k - ci * 9;
        int dy = (tap >= 6) ? 2 : (tap >= 3 ? 1 : 0);
        int dx = tap - dy * 3;
        int gr = r0 - 1 + dy, gc = px - 1 + dx;
        if ((unsigned)gr < 64u && (unsigned)gc < 64u)
          v = ap[((size_t)(gr * 64 + gc)) * 4 + ci];
      }
      smem[0][idx] = v;
    }
    bf16x8 bxa[4];
    #pragma unroll
    for (int gt = 0; gt < 4; ++gt)
      bxa[gt] = *(const bf16x8*)(wtA + ((w + 4 * gt) * 16 + n) * 32 + q * 8);
    // B prologue for chunk 0 (in flight across xin compute)
    BISSUE(0, bp, 0) BISSUE(1, bp, 1) BISSUE(2, bp, 2)
    __syncthreads();
    bf16x8 axv[4];
    #pragma unroll
    for (int mt = 0; mt < 4; ++mt)
      axv[mt] = *(const bf16x8*)(&smem[0][0] + (mt * 16 + n) * 32 + q * 8);
    #pragma unroll
    for (int mt = 0; mt < 4; ++mt)
      #pragma unroll
      for (int gt = 0; gt < 4; ++gt)
        acc[mt][gt] = __builtin_amdgcn_mfma_f32_16x16x32_bf16(axv[mt], bxa[gt], acc[mt][gt], 0, 0, 0);
    STAGE_WRITE(&smem[1][0]);
    __syncthreads();
    cur = 1;
  } else {
    BISSUE(0, bp, 0) BISSUE(1, bp, 1) BISSUE(2, bp, 2)
    STAGE_WRITE(&smem[0][0]);
    __syncthreads();
    cur = 0;
  }

  // ---- main chunk loop: one barrier per chunk, staged double-buffer ----
  for (int cg = 0; cg < ntot; ++cg) {
    const bool more = (cg + 1 < ntot);
    if (more) { SP_SET(cg + 1); STAGE_LOADS(); }   // issue-early (T14)
    const u16* bufc = &smem[cur][0];
    u16* bufn = &smem[cur ^ 1][0];
    const u16* bpn = bp + 73728;
    // av tap-0 prologue
    #pragma unroll
    for (int mt = 0; mt < 4; ++mt)
      av[0][mt] = *(const bf16x8*)(bufc + (mt * 16) * 32 + abase);
    #pragma unroll
    for (int tap = 0; tap < 9; ++tap) {
      // issue next tap's A-frags before this tap's MFMAs
      if (tap < 8) {
        const int t1 = tap + 1;
        const int dy = t1 / 3, dx = t1 - dy * 3;
        #pragma unroll
        for (int mt = 0; mt < 4; ++mt)
          av[t1 & 1][mt] = *(const bf16x8*)(bufc + (dy * 66 + dx + mt * 16) * 32 + abase);
      }
      #pragma unroll
      for (int mt = 0; mt < 4; ++mt)
        #pragma unroll
        for (int gt = 0; gt < 4; ++gt)
          acc[mt][gt] = __builtin_amdgcn_mfma_f32_16x16x32_bf16(av[tap & 1][mt], bq[tap % 3][gt], acc[mt][gt], 0, 0, 0);
      // B prefetch distance 3; slot (tap%3) just freed by the MFMAs above.
      // 9 % 3 == 0 keeps slot indices compile-time across the chunk boundary.
      if (tap + 3 < 9) {
        BISSUE((tap + 3) % 3, bp, tap + 3)
      } else if (more) {
        BISSUE((tap + 3) % 3, bpn, tap - 6)
      }
      if (tap == 5 && more) STAGE_WRITE(bufn)      // write-late into other buffer
    }
    __syncthreads();
    cur ^= 1;
    bp = bpn;
  }

  // ---- LSTM pointwise epilogue (lane-local: hc = 16w+n; gt = i,f,o,g) ----
  const int hc = w * 16 + n;
  const float bi = bias[hc], bfv = bias[64 + hc], bo = bias[128 + hc], bg = bias[192 + hc];
  float* cB = c_t + ((size_t)b * HW + r0 * 64) * 64 + hc;
  u16*   hB = h_t + (size_t)b * 262144 + (size_t)(hc >> 5) * 131072
            + (size_t)(r0 * 64) * 32 + (hc & 31);
  float* oB = out_f32 ? out_f32 + (size_t)b * out_bs + (size_t)hc * HW + r0 * 64 : (float*)0;
  #pragma unroll
  for (int mt = 0; mt < 4; ++mt) {
    #pragma unroll
    for (int reg = 0; reg < 4; ++reg) {
      int px = mt * 16 + q * 4 + reg;
      float xi = acc[mt][0][reg] + bi;
      float xf = acc[mt][1][reg] + bfv;
      float xo = acc[mt][2][reg] + bo;
      float xg = acc[mt][3][reg] + bg;
      float ii = sigmoid_f(xi), ff = sigmoid_f(xf), oo = sigmoid_f(xo), gg = tanh_f(xg);
      float cold = cB[(size_t)px * 64];
      float cnew = ff * cold + ii * gg;
      float hnew = oo * tanh_f(cnew);
      cB[(size_t)px * 64] = cnew;
      hB[(size_t)px * 32] = f2b(hnew);
      if (oB) oB[px] = hnew;
    }
  }
}

// ---- h1 final state: flat copy of out1[:, T-1] ----
__global__ void h1_final(const float* __restrict__ out1, float* __restrict__ dst) {
  size_t i = (size_t)blockIdx.x * 256 + threadIdx.x;  // 2,097,152
  size_t b = i >> 18, rem = i & 262143;
  dst[i] = out1[(b * NT + (NT - 1)) * 262144 + rem];
}

// ---- c1 final state: transpose [b][pix][hc] f32 -> [b][hc][pix] f32 ----
__global__ void c1_final(const float* __restrict__ c_t, float* __restrict__ dst) {
  __shared__ float t[64][65];
  int pb = blockIdx.x, b = blockIdx.y;
  int tx = threadIdx.x & 63, ty = threadIdx.x >> 6;
  for (int i = 0; i < 16; ++i) {
    int p = i * 4 + ty;
    t[p][tx] = c_t[((size_t)b * HW + pb * 64 + p) * 64 + tx];
  }
  __syncthreads();
  for (int i = 0; i < 16; ++i) {
    int hcv = i * 4 + ty;
    dst[(size_t)b * 262144 + (size_t)hcv * HW + pb * 64 + tx] = t[tx][hcv];
  }
}

extern "C" void kernel_launch(void* const* d_in, const int* in_sizes, int n_in,
                              void* d_out, int out_size, void* d_ws, size_t ws_size,
                              hipStream_t stream) {
  const float* x      = (const float*)d_in[0];
  const float* att_w1 = (const float*)d_in[1];
  const float* att_w2 = (const float*)d_in[2];
  const float* w0     = (const float*)d_in[3];
  const float* b0     = (const float*)d_in[4];
  const float* w1     = (const float*)d_in[5];
  const float* b1     = (const float*)d_in[6];
  float* out = (float*)d_out;
  char* ws = (char*)d_ws;

  // workspace layout (byte offsets, all 16B-aligned)
  u16*   xin_t = (u16*)(ws + 0);             // [8][16][4096][4] bf16, 4,194,304 B
  u16*   h0a   = (u16*)(ws + 4194304);       // [8][2][4096][32] bf16
  u16*   h0b   = (u16*)(ws + 8388608);
  u16*   h1a   = (u16*)(ws + 12582912);
  u16*   h1b   = (u16*)(ws + 16777216);
  u16*   zb    = (u16*)(ws + 20971520);      // 262,144 bf16 zeros (bstride 0)
  u16*   wtA0  = (u16*)(ws + 21495808);      // [256][32] bf16
  u16*   wtB0  = (u16*)(ws + 21512192);      // [2][9][256][32] bf16
  u16*   wtB1  = (u16*)(ws + 21807104);      // [4][9][256][32] bf16
  float* c0_t  = (float*)(ws + 22396928);    // [8][4096][64] f32
  float* c1_t  = (float*)(ws + 30785536);
  float* avg   = (float*)(ws + 39174144);    // 384
  float* mxb   = (float*)(ws + 39175680);    // 384
  if (ws_size < 39177216u) return;

  hipMemsetAsync(xin_t, 0, 4194304, stream);       // zeros slot ci=3
  hipMemsetAsync(zb, 0, 524288, stream);
  hipMemsetAsync(c0_t, 0, 8388608, stream);
  hipMemsetAsync(c1_t, 0, 8388608, stream);

  transform_wA<<<32, 256, 0, stream>>>(w0, wtA0);
  transform_wB<<<576, 256, 0, stream>>>(w0, wtB0, 67, 3, 2);
  transform_wB<<<1152, 256, 0, stream>>>(w1, wtB1, 128, 0, 4);
  att_reduce<<<NB * NT * 3, 256, 0, stream>>>(x, avg, mxb);
  att_apply<<<1572864 / 256, 256, 0, stream>>>(x, avg, mxb, att_w1, att_w2, xin_t);

  const long HB = 262144;   // h/c per-batch stride (elems)
  dim3 grid(64, 8);

  for (int t = 0; t < NT; ++t) {
    u16* h0_cur = (t & 1) ? h0b : h0a;
    const u16* h0_prev = (t == 0) ? zb : ((t & 1) ? h0a : h0b);
    long h0p_bs = (t == 0) ? 0L : HB;
    // layer 0: A0 = xin(3ch) ; s0 = h0_prev (2 chunks)
    conv_step<<<grid, 256, 0, stream>>>(
        xin_t + (size_t)t * 16384, (long)NT * 16384,
        wtA0,
        h0_prev, h0p_bs, 2,
        (const u16*)0, 0L, 0,
        wtB0, b0, c0_t, h0_cur, (float*)0, 0L);

    u16* h1_cur = (t & 1) ? h1b : h1a;
    const u16* h1_prev = (t == 0) ? zb : ((t & 1) ? h1a : h1b);
    long h1p_bs = (t == 0) ? 0L : HB;
    // layer 1: s0 = h0_cur (2 chunks), s1 = h1_prev (2 chunks); also scatter f32 out
    conv_step<<<grid, 256, 0, stream>>>(
        (const u16*)0, 0L,
        (const u16*)0,
        h0_cur, HB, 2,
        h1_prev, h1p_bs, 2,
        wtB1, b1, c1_t, h1_cur,
        out + (size_t)t * 262144, (long)NT * 262144);
  }

  h1_final<<<8192, 256, 0, stream>>>(out, out + 33554432);
  c1_final<<<grid, 256, 0, stream>>>(c1_t, out + 35651584);
}

// Round 2
// 933.745 us; speedup vs baseline: 1.2425x; 1.1398x over previous
//
#include <hip/hip_runtime.h>
#include <hip/hip_bf16.h>
#include <math.h>

#define HW 4096
#define NB 8
#define NT 16

typedef unsigned short u16;
typedef __attribute__((ext_vector_type(8))) short bf16x8;
typedef __attribute__((ext_vector_type(4))) float f32x4;

__device__ __forceinline__ float sigmoid_f(float x) {
  return 1.f / (1.f + __expf(-x));
}
__device__ __forceinline__ float tanh_f(float x) {
  float ax = fabsf(x);
  float e = __expf(2.f * ax);
  float t = 1.f - 2.f / (e + 1.f);
  return copysignf(t, x);
}
__device__ __forceinline__ u16 f2b(float v) {
  __hip_bfloat16 h = __float2bfloat16(v);
  return *(u16*)&h;
}

// ---- weight transform: w[256][CIN][3][3] f32 -> wtB[chunk][tap][gate][32ci] bf16
__global__ void transform_wB(const float* __restrict__ w, u16* __restrict__ wtB,
                             int CIN, int cinbase, int nch) {
  int idx = blockIdx.x * 256 + threadIdx.x;
  int total = nch * 9 * 256 * 32;
  if (idx >= total) return;
  int ci32 = idx & 31;
  int rest = idx >> 5;
  int gate = rest & 255;
  rest >>= 8;
  int tap = rest % 9;
  int chunk = rest / 9;
  int cin = cinbase + chunk * 32 + ci32;
  wtB[idx] = f2b(w[((size_t)gate * CIN + cin) * 9 + tap]);
}

// ---- layer0 xin-part weights: wtA[gate][32k] bf16, k = ci*9+tap (ci<3), pad 0
__global__ void transform_wA(const float* __restrict__ w0, u16* __restrict__ wtA) {
  int idx = blockIdx.x * 256 + threadIdx.x;  // 8192
  if (idx >= 8192) return;
  int k = idx & 31, gate = idx >> 5;
  u16 v = 0;
  if (k < 27) {
    int ci = (k >= 18) + (k >= 9);
    int tap = k - ci * 9;
    v = f2b(w0[((size_t)gate * 67 + ci) * 9 + tap]);
  }
  wtA[idx] = v;
}

// ---- attention reduce: per (b,t,c) avg & max over HW ----
__global__ void att_reduce(const float* __restrict__ x, float* __restrict__ avg,
                           float* __restrict__ mx) {
  int btc = blockIdx.x;  // 384
  const float* p = x + (size_t)btc * HW;
  float s = 0.f, m = -INFINITY;
  for (int i = threadIdx.x; i < HW; i += 256) {
    float v = p[i];
    s += v;
    m = fmaxf(m, v);
  }
  #pragma unroll
  for (int off = 32; off; off >>= 1) {
    s += __shfl_down(s, off, 64);
    m = fmaxf(m, __shfl_down(m, off, 64));
  }
  __shared__ float ss[4], sm[4];
  int wid = threadIdx.x >> 6, lane = threadIdx.x & 63;
  if (lane == 0) { ss[wid] = s; sm[wid] = m; }
  __syncthreads();
  if (threadIdx.x == 0) {
    avg[btc] = (ss[0] + ss[1] + ss[2] + ss[3]) * (1.f / 4096.f);
    mx[btc]  = fmaxf(fmaxf(sm[0], sm[1]), fmaxf(sm[2], sm[3]));
  }
}

// ---- attention apply -> xin_t[bt][pix][4ci] bf16 (channel-last, slot3 = 0) ----
__global__ void att_apply(const float* __restrict__ x, const float* __restrict__ avg,
                          const float* __restrict__ mx, const float* __restrict__ w1,
                          const float* __restrict__ w2, u16* __restrict__ xin_t) {
  size_t i = (size_t)blockIdx.x * 256 + threadIdx.x;  // 1,572,864 = (bt, c, pix)
  int pix = (int)(i & 4095);
  int c   = (int)((i >> 12) % 3);
  int bt  = (int)(i / (3 * HW));
  const float* a = avg + bt * 3;
  const float* m = mx + bt * 3;
  float ra = fmaxf(0.f, w1[0] * a[0] + w1[1] * a[1] + w1[2] * a[2]);
  float rm = fmaxf(0.f, w1[0] * m[0] + w1[1] * m[1] + w1[2] * m[2]);
  float sc = sigmoid_f(w2[c] * (ra + rm));
  xin_t[((size_t)bt * HW + pix) * 4 + c] = f2b(x[i] * sc);
}

// ---- per-role parameter set for the fused conv kernel ----
struct RoleP {
  const u16* a0; long a0_bs; const u16* wtA;   // layer0 xin path (a0 null otherwise)
  const u16* s0; long s0_bs; int s0_ch;        // h-style source 0 ([b][ch][4096][32])
  const u16* s1; long s1_bs; int s1_ch;        // h-style source 1
  const u16* wtB; const float* bias;
  float* c_t;                                  // [b][4096][64] f32
  u16* h_t;                                    // [b][2][4096][32] bf16
  float* out_f32; long out_bs;                 // [b][t][hc][4096] f32 (or null)
};

// ---- staging: one 16B DMA site via global_load_lds (linear LDS dest) ----
__device__ __forceinline__ void dma_site(const u16* sp, u16* bufn, int idx,
                                         const u16* zb, int r0) {
  int site = idx >> 2, sub = idx & 3;
  int r = site / 66, cc = site - r * 66;       // r may reach 3 in the pad region
  int gr = r0 - 1 + r, gc = cc - 1;
  const u16* g = ((unsigned)gr < 64u && (unsigned)gc < 64u)
               ? sp + (size_t)(gr * 64 + gc) * 32 + sub * 8
               : zb;                            // OOB lanes read the zero page
  u16* l = bufn + (size_t)(idx & ~63) * 8;      // wave-uniform LDS base; HW adds lane*16
  __builtin_amdgcn_global_load_lds(
      (const __attribute__((address_space(1))) unsigned int*)g,
      (__attribute__((address_space(3))) unsigned int*)l, 16, 0, 0);
}

__device__ __forceinline__ void dma_chunk(const u16* sp, u16* bufn, const u16* zb,
                                          int r0, int tid) {
  #pragma unroll
  for (int it = 0; it < 3; ++it) dma_site(sp, bufn, it * 256 + tid, zb, r0);
  if (tid < 64) dma_site(sp, bufn, 768 + tid, zb, r0);   // wave-0-uniform tail
}

#define BQ_LOAD(S, BASE, TP)                                              \
  { _Pragma("unroll")                                                     \
    for (int _g = 0; _g < 4; ++_g)                                        \
      bq[S][_g] = *(const bf16x8*)((BASE) + (TP) * 8192 + _g * 2048); }

// one 9-tap chunk; PAR = global tap parity at chunk start (ring-2, distance-1)
template <int PAR>
__device__ __forceinline__ void chunk_compute(const u16* bufc, const u16* bpc,
                                              const u16* bpn, bool more,
                                              bf16x8 (&bq)[2][4], f32x4 (&acc)[4][4],
                                              int abase) {
  #pragma unroll
  for (int tap = 0; tap < 9; ++tap) {
    if (tap < 8) { BQ_LOAD((tap + 1 + PAR) & 1, bpc, tap + 1) }
    else if (more) { BQ_LOAD((1 + PAR) & 1, bpn, 0) }
    const int dy = tap / 3, dx = tap - dy * 3;
    bf16x8 av[4];
    #pragma unroll
    for (int mt = 0; mt < 4; ++mt)
      av[mt] = *(const bf16x8*)(bufc + (dy * 66 + dx + mt * 16) * 32 + abase);
    #pragma unroll
    for (int mt = 0; mt < 4; ++mt)
      #pragma unroll
      for (int gt = 0; gt < 4; ++gt)
        acc[mt][gt] = __builtin_amdgcn_mfma_f32_16x16x32_bf16(
            av[mt], bq[(tap + PAR) & 1][gt], acc[mt][gt], 0, 0, 0);
  }
}

#define SP_SET(CG)                                                           \
  sp = ((CG) < P.s0_ch)                                                      \
     ? P.s0 + (size_t)b * P.s0_bs + (size_t)(CG) * 131072                    \
     : P.s1 + (size_t)b * P.s1_bs + (size_t)((CG) - P.s0_ch) * 131072;

// ---- fused dual-role implicit-GEMM conv + LSTM pointwise ----
// grid (64 rows, 8 batch, nz); role = blockIdx.z + zbase: 0 = layer0[t], 1 = layer1[t-1]
// 4 waves/block, 4 blocks/CU (VGPR<=128 via launch_bounds), global_load_lds staging.
__global__ __launch_bounds__(256, 4) void conv_step(
    RoleP r0p, RoleP r1p, int zbase, const u16* __restrict__ zb)
{
  __shared__ __align__(16) u16 smem[2][6656];   // 2 x 13,312 B (6336 used + DMA pad)
  __shared__ __align__(16) u16 xtile[2048];     // layer0 xin im2col tile
  const RoleP P = (blockIdx.z + zbase) ? r1p : r0p;
  const int r0 = blockIdx.x, b = blockIdx.y;
  const int tid = threadIdx.x;
  const int w = tid >> 6, lane = tid & 63;
  const int n = lane & 15, q = lane >> 4;
  const int abase = n * 32 + q * 8;
  const int ntot = P.s0_ch + P.s1_ch;           // 2 (layer0) or 4 (layer1), always even

  f32x4 acc[4][4];
  #pragma unroll
  for (int mt = 0; mt < 4; ++mt)
    #pragma unroll
    for (int gt = 0; gt < 4; ++gt)
      acc[mt][gt] = (f32x4){0.f, 0.f, 0.f, 0.f};

  const u16* bp0 = P.wtB + (size_t)(w * 16 + n) * 32 + q * 8;
  bf16x8 bq[2][4];
  const u16* sp;

  // ---- prologue: chunk-0 DMA + B tap-0, overlap with layer-0 xin staging ----
  SP_SET(0);
  dma_chunk(sp, &smem[0][0], zb, r0, tid);
  BQ_LOAD(0, bp0, 0)
  if (P.a0) {
    const u16* ap = P.a0 + (size_t)b * P.a0_bs;
    for (int idx = tid; idx < 2048; idx += 256) {
      int k = idx & 31, px = idx >> 5;
      u16 v = 0;
      if (k < 27) {
        int ci = (k >= 18) + (k >= 9);
        int tap = k - ci * 9;
        int dy = (tap >= 6) ? 2 : (tap >= 3 ? 1 : 0);
        int dx = tap - dy * 3;
        int gr = r0 - 1 + dy, gc = px - 1 + dx;
        if ((unsigned)gr < 64u && (unsigned)gc < 64u)
          v = ap[((size_t)(gr * 64 + gc)) * 4 + ci];
      }
      xtile[idx] = v;
    }
  }
  __syncthreads();   // drains DMA (vmcnt0) + xtile writes
  if (P.a0) {
    bf16x8 bxa[4], axv[4];
    #pragma unroll
    for (int gt = 0; gt < 4; ++gt)
      bxa[gt] = *(const bf16x8*)(P.wtA + ((w + 4 * gt) * 16 + n) * 32 + q * 8);
    #pragma unroll
    for (int mt = 0; mt < 4; ++mt)
      axv[mt] = *(const bf16x8*)(xtile + (mt * 16 + n) * 32 + q * 8);
    #pragma unroll
    for (int mt = 0; mt < 4; ++mt)
      #pragma unroll
      for (int gt = 0; gt < 4; ++gt)
        acc[mt][gt] = __builtin_amdgcn_mfma_f32_16x16x32_bf16(axv[mt], bxa[gt], acc[mt][gt], 0, 0, 0);
  }

  // ---- main chunk loop, unrolled x2 (compile-time ring parity) ----
  int cur = 0;
  for (int cg = 0; cg < ntot; cg += 2) {
    {   // even-parity chunk: cg (cg+1 < ntot always since ntot even)
      SP_SET(cg + 1);
      dma_chunk(sp, &smem[cur ^ 1][0], zb, r0, tid);
      chunk_compute<0>(&smem[cur][0], bp0 + (size_t)cg * 73728,
                       bp0 + (size_t)(cg + 1) * 73728, true, bq, acc, abase);
      __syncthreads();
      cur ^= 1;
    }
    {   // odd-parity chunk: cg+1
      bool more = (cg + 2 < ntot);
      if (more) {
        SP_SET(cg + 2);
        dma_chunk(sp, &smem[cur ^ 1][0], zb, r0, tid);
      }
      chunk_compute<1>(&smem[cur][0], bp0 + (size_t)(cg + 1) * 73728,
                       bp0 + (size_t)(cg + 2) * 73728, more, bq, acc, abase);
      __syncthreads();
      cur ^= 1;
    }
  }

  // ---- LSTM pointwise epilogue (lane-local: hc = 16w+n; gt = i,f,o,g) ----
  const int hc = w * 16 + n;
  const float bi = P.bias[hc], bfv = P.bias[64 + hc], bo = P.bias[128 + hc], bg = P.bias[192 + hc];
  float* cB = P.c_t + ((size_t)b * HW + r0 * 64) * 64 + hc;
  u16*   hB = P.h_t + (size_t)b * 262144 + (size_t)(hc >> 5) * 131072
            + (size_t)(r0 * 64) * 32 + (hc & 31);
  float* tbuf = (float*)&smem[0][0];            // 64px x 65 floats (16,640 B)
  #pragma unroll
  for (int mt = 0; mt < 4; ++mt) {
    #pragma unroll
    for (int reg = 0; reg < 4; ++reg) {
      int px = mt * 16 + q * 4 + reg;
      float xi = acc[mt][0][reg] + bi;
      float xf = acc[mt][1][reg] + bfv;
      float xo = acc[mt][2][reg] + bo;
      float xg = acc[mt][3][reg] + bg;
      float ii = sigmoid_f(xi), ff = sigmoid_f(xf), oo = sigmoid_f(xo), gg = tanh_f(xg);
      float cold = cB[(size_t)px * 64];
      float cnew = ff * cold + ii * gg;
      float hnew = oo * tanh_f(cnew);
      cB[(size_t)px * 64] = cnew;
      hB[(size_t)px * 32] = f2b(hnew);
      if (P.out_f32) tbuf[px * 65 + hc] = hnew;
    }
  }
  if (P.out_f32) {   // coalesced out write via LDS transpose
    __syncthreads();
    int hc2 = tid >> 2, qq = tid & 3;
    float* orow = P.out_f32 + (size_t)b * P.out_bs + (size_t)hc2 * HW + r0 * 64;
    #pragma unroll
    for (int j = 0; j < 4; ++j) {
      int p0x = qq * 4 + j * 16;
      float4 v = make_float4(tbuf[(p0x + 0) * 65 + hc2], tbuf[(p0x + 1) * 65 + hc2],
                             tbuf[(p0x + 2) * 65 + hc2], tbuf[(p0x + 3) * 65 + hc2]);
      *(float4*)(orow + p0x) = v;
    }
  }
}

// ---- h1 final state: flat copy of out1[:, T-1] ----
__global__ void h1_final(const float* __restrict__ out1, float* __restrict__ dst) {
  size_t i = (size_t)blockIdx.x * 256 + threadIdx.x;  // 2,097,152
  size_t b = i >> 18, rem = i & 262143;
  dst[i] = out1[(b * NT + (NT - 1)) * 262144 + rem];
}

// ---- c1 final state: transpose [b][pix][hc] f32 -> [b][hc][pix] f32 ----
__global__ void c1_final(const float* __restrict__ c_t, float* __restrict__ dst) {
  __shared__ float t[64][65];
  int pb = blockIdx.x, b = blockIdx.y;
  int tx = threadIdx.x & 63, ty = threadIdx.x >> 6;
  for (int i = 0; i < 16; ++i) {
    int p = i * 4 + ty;
    t[p][tx] = c_t[((size_t)b * HW + pb * 64 + p) * 64 + tx];
  }
  __syncthreads();
  for (int i = 0; i < 16; ++i) {
    int hcv = i * 4 + ty;
    dst[(size_t)b * 262144 + (size_t)hcv * HW + pb * 64 + tx] = t[tx][hcv];
  }
}

extern "C" void kernel_launch(void* const* d_in, const int* in_sizes, int n_in,
                              void* d_out, int out_size, void* d_ws, size_t ws_size,
                              hipStream_t stream) {
  const float* x      = (const float*)d_in[0];
  const float* att_w1 = (const float*)d_in[1];
  const float* att_w2 = (const float*)d_in[2];
  const float* w0     = (const float*)d_in[3];
  const float* b0     = (const float*)d_in[4];
  const float* w1     = (const float*)d_in[5];
  const float* b1     = (const float*)d_in[6];
  float* out = (float*)d_out;
  char* ws = (char*)d_ws;

  // workspace layout (byte offsets, all 16B-aligned)
  u16*   xin_t = (u16*)(ws + 0);             // [8][16][4096][4] bf16, 4,194,304 B
  u16*   h0a   = (u16*)(ws + 4194304);       // [8][2][4096][32] bf16
  u16*   h0b   = (u16*)(ws + 8388608);
  u16*   h1a   = (u16*)(ws + 12582912);
  u16*   h1b   = (u16*)(ws + 16777216);
  u16*   zb    = (u16*)(ws + 20971520);      // 262,144 bf16 zeros (bstride 0)
  u16*   wtA0  = (u16*)(ws + 21495808);      // [256][32] bf16
  u16*   wtB0  = (u16*)(ws + 21512192);      // [2][9][256][32] bf16
  u16*   wtB1  = (u16*)(ws + 21807104);      // [4][9][256][32] bf16
  float* c0_t  = (float*)(ws + 22396928);    // [8][4096][64] f32
  float* c1_t  = (float*)(ws + 30785536);
  float* avg   = (float*)(ws + 39174144);    // 384
  float* mxb   = (float*)(ws + 39175680);    // 384
  if (ws_size < 39177216u) return;

  hipMemsetAsync(xin_t, 0, 4194304, stream);       // zeros slot ci=3
  hipMemsetAsync(zb, 0, 524288, stream);
  hipMemsetAsync(c0_t, 0, 8388608, stream);
  hipMemsetAsync(c1_t, 0, 8388608, stream);

  transform_wA<<<32, 256, 0, stream>>>(w0, wtA0);
  transform_wB<<<576, 256, 0, stream>>>(w0, wtB0, 67, 3, 2);
  transform_wB<<<1152, 256, 0, stream>>>(w1, wtB1, 128, 0, 4);
  att_reduce<<<NB * NT * 3, 256, 0, stream>>>(x, avg, mxb);
  att_apply<<<1572864 / 256, 256, 0, stream>>>(x, avg, mxb, att_w1, att_w2, xin_t);

  const long HB = 262144;   // h/c per-batch stride (elems)

  // fused schedule: launch s runs layer0[t=s] (role 0) and layer1[t=s-1] (role 1)
  for (int s = 0; s <= NT; ++s) {
    bool has0 = (s < NT), has1 = (s > 0);
    RoleP p0 = {}, p1 = {};
    if (has0) {
      int t = s;
      p0.a0 = xin_t + (size_t)t * 16384; p0.a0_bs = (long)NT * 16384; p0.wtA = wtA0;
      p0.s0 = (t == 0) ? zb : ((t & 1) ? h0a : h0b);
      p0.s0_bs = (t == 0) ? 0L : HB; p0.s0_ch = 2;
      p0.s1 = zb; p0.s1_bs = 0L; p0.s1_ch = 0;
      p0.wtB = wtB0; p0.bias = b0; p0.c_t = c0_t;
      p0.h_t = (t & 1) ? h0b : h0a;
      p0.out_f32 = (float*)0; p0.out_bs = 0L;
    }
    if (has1) {
      int t = s - 1;
      p1.a0 = (const u16*)0; p1.a0_bs = 0L; p1.wtA = (const u16*)0;
      p1.s0 = (t & 1) ? h0b : h0a;            // h0[t], written by launch s-1
      p1.s0_bs = HB; p1.s0_ch = 2;
      p1.s1 = (t == 0) ? zb : ((t & 1) ? h1a : h1b);
      p1.s1_bs = (t == 0) ? 0L : HB; p1.s1_ch = 2;
      p1.wtB = wtB1; p1.bias = b1; p1.c_t = c1_t;
      p1.h_t = (t & 1) ? h1b : h1a;
      p1.out_f32 = out + (size_t)t * 262144; p1.out_bs = (long)NT * 262144;
    }
    int zbase = has0 ? 0 : 1;
    int zn = (has0 && has1) ? 2 : 1;
    conv_step<<<dim3(64, 8, zn), 256, 0, stream>>>(p0, p1, zbase, zb);
  }

  h1_final<<<8192, 256, 0, stream>>>(out, out + 33554432);
  c1_final<<<dim3(64, 8), 256, 0, stream>>>(c1_t, out + 35651584);
}

// Round 3
// 918.806 us; speedup vs baseline: 1.2627x; 1.0163x over previous
//
#include <hip/hip_runtime.h>
#include <hip/hip_bf16.h>
#include <math.h>

#define HW 4096
#define NB 8
#define NT 16

typedef unsigned short u16;
typedef __attribute__((ext_vector_type(8))) short bf16x8;
typedef __attribute__((ext_vector_type(4))) float f32x4;

__device__ __forceinline__ float sigmoid_f(float x) {
  return 1.f / (1.f + __expf(-x));
}
__device__ __forceinline__ float tanh_f(float x) {
  float ax = fabsf(x);
  float e = __expf(2.f * ax);
  float t = 1.f - 2.f / (e + 1.f);
  return copysignf(t, x);
}
__device__ __forceinline__ u16 f2b(float v) {
  __hip_bfloat16 h = __float2bfloat16(v);
  return *(u16*)&h;
}

// ---- weight transform: w[256][CIN][3][3] f32 -> wtB[chunk][tap][gate][32ci] bf16
__global__ void transform_wB(const float* __restrict__ w, u16* __restrict__ wtB,
                             int CIN, int cinbase, int nch) {
  int idx = blockIdx.x * 256 + threadIdx.x;
  int total = nch * 9 * 256 * 32;
  if (idx >= total) return;
  int ci32 = idx & 31;
  int rest = idx >> 5;
  int gate = rest & 255;
  rest >>= 8;
  int tap = rest % 9;
  int chunk = rest / 9;
  int cin = cinbase + chunk * 32 + ci32;
  wtB[idx] = f2b(w[((size_t)gate * CIN + cin) * 9 + tap]);
}

// ---- layer0 xin-part weights: wtA[gate][32k] bf16, k = ci*9+tap (ci<3), pad 0
__global__ void transform_wA(const float* __restrict__ w0, u16* __restrict__ wtA) {
  int idx = blockIdx.x * 256 + threadIdx.x;  // 8192
  if (idx >= 8192) return;
  int k = idx & 31, gate = idx >> 5;
  u16 v = 0;
  if (k < 27) {
    int ci = (k >= 18) + (k >= 9);
    int tap = k - ci * 9;
    v = f2b(w0[((size_t)gate * 67 + ci) * 9 + tap]);
  }
  wtA[idx] = v;
}

// ---- attention reduce: per (b,t,c) avg & max over HW ----
__global__ void att_reduce(const float* __restrict__ x, float* __restrict__ avg,
                           float* __restrict__ mx) {
  int btc = blockIdx.x;  // 384
  const float* p = x + (size_t)btc * HW;
  float s = 0.f, m = -INFINITY;
  for (int i = threadIdx.x; i < HW; i += 256) {
    float v = p[i];
    s += v;
    m = fmaxf(m, v);
  }
  #pragma unroll
  for (int off = 32; off; off >>= 1) {
    s += __shfl_down(s, off, 64);
    m = fmaxf(m, __shfl_down(m, off, 64));
  }
  __shared__ float ss[4], sm[4];
  int wid = threadIdx.x >> 6, lane = threadIdx.x & 63;
  if (lane == 0) { ss[wid] = s; sm[wid] = m; }
  __syncthreads();
  if (threadIdx.x == 0) {
    avg[btc] = (ss[0] + ss[1] + ss[2] + ss[3]) * (1.f / 4096.f);
    mx[btc]  = fmaxf(fmaxf(sm[0], sm[1]), fmaxf(sm[2], sm[3]));
  }
}

// ---- attention apply -> xin_t[bt][pix][4ci] bf16 (channel-last, slot3 = 0) ----
__global__ void att_apply(const float* __restrict__ x, const float* __restrict__ avg,
                          const float* __restrict__ mx, const float* __restrict__ w1,
                          const float* __restrict__ w2, u16* __restrict__ xin_t) {
  size_t i = (size_t)blockIdx.x * 256 + threadIdx.x;  // 1,572,864 = (bt, c, pix)
  int pix = (int)(i & 4095);
  int c   = (int)((i >> 12) % 3);
  int bt  = (int)(i / (3 * HW));
  const float* a = avg + bt * 3;
  const float* m = mx + bt * 3;
  float ra = fmaxf(0.f, w1[0] * a[0] + w1[1] * a[1] + w1[2] * a[2]);
  float rm = fmaxf(0.f, w1[0] * m[0] + w1[1] * m[1] + w1[2] * m[2]);
  float sc = sigmoid_f(w2[c] * (ra + rm));
  xin_t[((size_t)bt * HW + pix) * 4 + c] = f2b(x[i] * sc);
}

// ---- per-role parameter set for the fused conv kernel ----
struct RoleP {
  const u16* a0; long a0_bs; const u16* wtA;   // layer0 xin path (a0 null otherwise)
  const u16* s0; long s0_bs; int s0_ch;        // h-style source 0 ([b][ch][4096][32])
  const u16* s1; long s1_bs; int s1_ch;        // h-style source 1
  const u16* wtB; const float* bias;
  float* c_t;                                  // [b][4096][64] f32
  u16* h_t;                                    // [b][2][4096][32] bf16
  float* out_f32; long out_bs;                 // [b][t][hc][4096] f32 (or null)
};

// ---- staging: chunk tile = 4 input rows x 66 sites x 32 ch, granule = 16 B ----
// granule idx g in [0,1088): site = g>>2, sub = g&3; LDS linear at g*8 elems.
// sites 0..263 real (row = site/66, col = site%66 - 1), >=264 = tail pad from zb.
__device__ __forceinline__ void dma_site(const u16* sp, u16* bufn, int idx,
                                         const u16* zb, int r0g) {
  int site = idx >> 2, sub = idx & 3;
  int r = site / 66, cc = site - r * 66;
  int gr = r0g - 1 + r, gc = cc - 1;
  const u16* g = (site < 264 && (unsigned)gr < 64u && (unsigned)gc < 64u)
               ? sp + (size_t)(gr * 64 + gc) * 32 + sub * 8
               : zb;                            // OOB / pad lanes read the zero page
  u16* l = bufn + (size_t)(idx & ~63) * 8;      // wave-uniform LDS base; HW adds lane*16
  __builtin_amdgcn_global_load_lds(
      (const __attribute__((address_space(1))) unsigned int*)g,
      (__attribute__((address_space(3))) unsigned int*)l, 16, 0, 0);
}

__device__ __forceinline__ void dma_chunk(const u16* sp, u16* bufn, const u16* zb,
                                          int r0g, int tid) {
  #pragma unroll
  for (int it = 0; it < 2; ++it) dma_site(sp, bufn, it * 512 + tid, zb, r0g);
  if (tid < 64) dma_site(sp, bufn, 1024 + tid, zb, r0g);   // full-wave tail (pads to 1088)
}

#define BQ_LOAD(S, BASE, TP)                                              \
  { _Pragma("unroll")                                                     \
    for (int _g = 0; _g < 4; ++_g)                                        \
      bq[S][_g] = *(const bf16x8*)((BASE) + (TP) * 8192 + _g * 2048); }

// one 9-tap chunk; PAR = global tap parity at chunk start (ring-2, distance-1)
// abase2 = mh*2112 + n*32 + q*8 (wave row-half baked in)
template <int PAR>
__device__ __forceinline__ void chunk_compute(const u16* bufc, const u16* bpc,
                                              const u16* bpn, bool more,
                                              bf16x8 (&bq)[2][4], f32x4 (&acc)[4][4],
                                              int abase2) {
  #pragma unroll
  for (int tap = 0; tap < 9; ++tap) {
    if (tap < 8) { BQ_LOAD((tap + 1 + PAR) & 1, bpc, tap + 1) }
    else if (more) { BQ_LOAD((1 + PAR) & 1, bpn, 0) }
    const int dy = tap / 3, dx = tap - dy * 3;
    bf16x8 av[4];
    #pragma unroll
    for (int mt = 0; mt < 4; ++mt)
      av[mt] = *(const bf16x8*)(bufc + abase2 + dy * 2112 + dx * 32 + mt * 512);
    #pragma unroll
    for (int mt = 0; mt < 4; ++mt)
      #pragma unroll
      for (int gt = 0; gt < 4; ++gt)
        acc[mt][gt] = __builtin_amdgcn_mfma_f32_16x16x32_bf16(
            av[mt], bq[(tap + PAR) & 1][gt], acc[mt][gt], 0, 0, 0);
  }
}

#define SP_SET(CG)                                                           \
  sp = ((CG) < P.s0_ch)                                                      \
     ? P.s0 + (size_t)b * P.s0_bs + (size_t)(CG) * 131072                    \
     : P.s1 + (size_t)b * P.s1_bs + (size_t)((CG) - P.s0_ch) * 131072;

// ---- fused dual-role implicit-GEMM conv + LSTM pointwise, 2 rows / block ----
// grid (32 row-pairs, 8 batch, nz); role = blockIdx.z + zbase.
// 8 waves: wave w -> (gc = w>>1 gate-column, mh = w&1 row-half). Wave pairs
// (2k,2k+1) read IDENTICAL B streams (L1 dedup) -> B-from-L2 per output halved.
__global__ __launch_bounds__(512, 4) void conv_step(
    RoleP r0p, RoleP r1p, int zbase, const u16* __restrict__ zb)
{
  __shared__ __align__(16) u16 smem[2][8704];   // 2 x 17,408 B (8448 used + tail pad)
  __shared__ __align__(16) u16 xtile[4096];     // layer0 xin im2col tile (2 rows)
  const RoleP P = (blockIdx.z + zbase) ? r1p : r0p;
  const int r0g = blockIdx.x * 2, b = blockIdx.y;
  const int tid = threadIdx.x;
  const int w = tid >> 6, lane = tid & 63;
  const int n = lane & 15, q = lane >> 4;
  const int gc = w >> 1, mh = w & 1;
  const int abase2 = mh * 2112 + n * 32 + q * 8;
  const int ntot = P.s0_ch + P.s1_ch;           // 2 (layer0) or 4 (layer1), always even

  f32x4 acc[4][4];
  #pragma unroll
  for (int mt = 0; mt < 4; ++mt)
    #pragma unroll
    for (int gt = 0; gt < 4; ++gt)
      acc[mt][gt] = (f32x4){0.f, 0.f, 0.f, 0.f};

  const u16* bp0 = P.wtB + (size_t)(gc * 16 + n) * 32 + q * 8;
  bf16x8 bq[2][4];
  const u16* sp;

  // ---- prologue: chunk-0 DMA + B tap-0, overlap with layer-0 xin staging ----
  SP_SET(0);
  dma_chunk(sp, &smem[0][0], zb, r0g, tid);
  BQ_LOAD(0, bp0, 0)
  if (P.a0) {
    const u16* ap = P.a0 + (size_t)b * P.a0_bs;
    for (int idx = tid; idx < 4096; idx += 512) {
      int row = idx >> 11, rest = idx & 2047;
      int k = rest & 31, px = rest >> 5;
      u16 v = 0;
      if (k < 27) {
        int ci = (k >= 18) + (k >= 9);
        int tap = k - ci * 9;
        int dy = (tap >= 6) ? 2 : (tap >= 3 ? 1 : 0);
        int dx = tap - dy * 3;
        int gr = r0g + row - 1 + dy, gcl = px - 1 + dx;
        if ((unsigned)gr < 64u && (unsigned)gcl < 64u)
          v = ap[((size_t)(gr * 64 + gcl)) * 4 + ci];
      }
      xtile[idx] = v;
    }
  }
  __syncthreads();   // drains DMA (vmcnt0) + xtile writes
  if (P.a0) {
    bf16x8 bxa[4], axv[4];
    #pragma unroll
    for (int gt = 0; gt < 4; ++gt)
      bxa[gt] = *(const bf16x8*)(P.wtA + ((gc + 4 * gt) * 16 + n) * 32 + q * 8);
    #pragma unroll
    for (int mt = 0; mt < 4; ++mt)
      axv[mt] = *(const bf16x8*)(xtile + mh * 2048 + (mt * 16 + n) * 32 + q * 8);
    #pragma unroll
    for (int mt = 0; mt < 4; ++mt)
      #pragma unroll
      for (int gt = 0; gt < 4; ++gt)
        acc[mt][gt] = __builtin_amdgcn_mfma_f32_16x16x32_bf16(axv[mt], bxa[gt], acc[mt][gt], 0, 0, 0);
  }

  // ---- main chunk loop, unrolled x2 (compile-time ring parity) ----
  int cur = 0;
  for (int cg = 0; cg < ntot; cg += 2) {
    {   // even-parity chunk: cg (cg+1 < ntot always since ntot even)
      SP_SET(cg + 1);
      dma_chunk(sp, &smem[cur ^ 1][0], zb, r0g, tid);
      chunk_compute<0>(&smem[cur][0], bp0 + (size_t)cg * 73728,
                       bp0 + (size_t)(cg + 1) * 73728, true, bq, acc, abase2);
      __syncthreads();
      cur ^= 1;
    }
    {   // odd-parity chunk: cg+1
      bool more = (cg + 2 < ntot);
      if (more) {
        SP_SET(cg + 2);
        dma_chunk(sp, &smem[cur ^ 1][0], zb, r0g, tid);
      }
      chunk_compute<1>(&smem[cur][0], bp0 + (size_t)(cg + 1) * 73728,
                       bp0 + (size_t)(cg + 2) * 73728, more, bq, acc, abase2);
      __syncthreads();
      cur ^= 1;
    }
  }

  // ---- LSTM pointwise epilogue (lane-local: hc = 16*gc+n; gt = i,f,o,g) ----
  const int hc = gc * 16 + n;
  const int orow_g = r0g + mh;                  // this wave's output row
  const float bi = P.bias[hc], bfv = P.bias[64 + hc], bo = P.bias[128 + hc], bg = P.bias[192 + hc];
  float* cB = P.c_t + ((size_t)b * HW + orow_g * 64) * 64 + hc;
  u16*   hB = P.h_t + (size_t)b * 262144 + (size_t)(hc >> 5) * 131072
            + (size_t)(orow_g * 64) * 32 + (hc & 31);
  float* tbuf = (float*)&smem[0][0];            // 128 px x 65 floats (33,280 B)
  #pragma unroll
  for (int mt = 0; mt < 4; ++mt) {
    #pragma unroll
    for (int reg = 0; reg < 4; ++reg) {
      int px = mt * 16 + q * 4 + reg;           // local px within this row
      float xi = acc[mt][0][reg] + bi;
      float xf = acc[mt][1][reg] + bfv;
      float xo = acc[mt][2][reg] + bo;
      float xg = acc[mt][3][reg] + bg;
      float ii = sigmoid_f(xi), ff = sigmoid_f(xf), oo = sigmoid_f(xo), gg = tanh_f(xg);
      float cold = cB[(size_t)px * 64];
      float cnew = ff * cold + ii * gg;
      float hnew = oo * tanh_f(cnew);
      cB[(size_t)px * 64] = cnew;
      hB[(size_t)px * 32] = f2b(hnew);
      if (P.out_f32) tbuf[(mh * 64 + px) * 65 + hc] = hnew;
    }
  }
  if (P.out_f32) {   // coalesced out write via LDS transpose (both rows)
    __syncthreads();
    int hc2 = (tid >> 2) & 63, qq = tid & 3, rw = tid >> 8;
    float* orow = P.out_f32 + (size_t)b * P.out_bs + (size_t)hc2 * HW + (r0g + rw) * 64;
    #pragma unroll
    for (int j = 0; j < 4; ++j) {
      int p0x = qq * 4 + j * 16;
      float4 v = make_float4(tbuf[(rw * 64 + p0x + 0) * 65 + hc2],
                             tbuf[(rw * 64 + p0x + 1) * 65 + hc2],
                             tbuf[(rw * 64 + p0x + 2) * 65 + hc2],
                             tbuf[(rw * 64 + p0x + 3) * 65 + hc2]);
      *(float4*)(orow + p0x) = v;
    }
  }
}

// ---- h1 final state: flat copy of out1[:, T-1] ----
__global__ void h1_final(const float* __restrict__ out1, float* __restrict__ dst) {
  size_t i = (size_t)blockIdx.x * 256 + threadIdx.x;  // 2,097,152
  size_t b = i >> 18, rem = i & 262143;
  dst[i] = out1[(b * NT + (NT - 1)) * 262144 + rem];
}

// ---- c1 final state: transpose [b][pix][hc] f32 -> [b][hc][pix] f32 ----
__global__ void c1_final(const float* __restrict__ c_t, float* __restrict__ dst) {
  __shared__ float t[64][65];
  int pb = blockIdx.x, b = blockIdx.y;
  int tx = threadIdx.x & 63, ty = threadIdx.x >> 6;
  for (int i = 0; i < 16; ++i) {
    int p = i * 4 + ty;
    t[p][tx] = c_t[((size_t)b * HW + pb * 64 + p) * 64 + tx];
  }
  __syncthreads();
  for (int i = 0; i < 16; ++i) {
    int hcv = i * 4 + ty;
    dst[(size_t)b * 262144 + (size_t)hcv * HW + pb * 64 + tx] = t[tx][hcv];
  }
}

extern "C" void kernel_launch(void* const* d_in, const int* in_sizes, int n_in,
                              void* d_out, int out_size, void* d_ws, size_t ws_size,
                              hipStream_t stream) {
  const float* x      = (const float*)d_in[0];
  const float* att_w1 = (const float*)d_in[1];
  const float* att_w2 = (const float*)d_in[2];
  const float* w0     = (const float*)d_in[3];
  const float* b0     = (const float*)d_in[4];
  const float* w1     = (const float*)d_in[5];
  const float* b1     = (const float*)d_in[6];
  float* out = (float*)d_out;
  char* ws = (char*)d_ws;

  // workspace layout (byte offsets, all 16B-aligned)
  u16*   xin_t = (u16*)(ws + 0);             // [8][16][4096][4] bf16, 4,194,304 B
  u16*   h0a   = (u16*)(ws + 4194304);       // [8][2][4096][32] bf16
  u16*   h0b   = (u16*)(ws + 8388608);
  u16*   h1a   = (u16*)(ws + 12582912);
  u16*   h1b   = (u16*)(ws + 16777216);
  u16*   zb    = (u16*)(ws + 20971520);      // 262,144 bf16 zeros (bstride 0)
  u16*   wtA0  = (u16*)(ws + 21495808);      // [256][32] bf16
  u16*   wtB0  = (u16*)(ws + 21512192);      // [2][9][256][32] bf16
  u16*   wtB1  = (u16*)(ws + 21807104);      // [4][9][256][32] bf16
  float* c0_t  = (float*)(ws + 22396928);    // [8][4096][64] f32
  float* c1_t  = (float*)(ws + 30785536);
  float* avg   = (float*)(ws + 39174144);    // 384
  float* mxb   = (float*)(ws + 39175680);    // 384
  if (ws_size < 39177216u) return;

  hipMemsetAsync(xin_t, 0, 4194304, stream);       // zeros slot ci=3
  hipMemsetAsync(zb, 0, 524288, stream);
  hipMemsetAsync(c0_t, 0, 8388608, stream);
  hipMemsetAsync(c1_t, 0, 8388608, stream);

  transform_wA<<<32, 256, 0, stream>>>(w0, wtA0);
  transform_wB<<<576, 256, 0, stream>>>(w0, wtB0, 67, 3, 2);
  transform_wB<<<1152, 256, 0, stream>>>(w1, wtB1, 128, 0, 4);
  att_reduce<<<NB * NT * 3, 256, 0, stream>>>(x, avg, mxb);
  att_apply<<<1572864 / 256, 256, 0, stream>>>(x, avg, mxb, att_w1, att_w2, xin_t);

  const long HB = 262144;   // h/c per-batch stride (elems)

  // fused schedule: launch s runs layer0[t=s] (role 0) and layer1[t=s-1] (role 1)
  for (int s = 0; s <= NT; ++s) {
    bool has0 = (s < NT), has1 = (s > 0);
    RoleP p0 = {}, p1 = {};
    if (has0) {
      int t = s;
      p0.a0 = xin_t + (size_t)t * 16384; p0.a0_bs = (long)NT * 16384; p0.wtA = wtA0;
      p0.s0 = (t == 0) ? zb : ((t & 1) ? h0a : h0b);
      p0.s0_bs = (t == 0) ? 0L : HB; p0.s0_ch = 2;
      p0.s1 = zb; p0.s1_bs = 0L; p0.s1_ch = 0;
      p0.wtB = wtB0; p0.bias = b0; p0.c_t = c0_t;
      p0.h_t = (t & 1) ? h0b : h0a;
      p0.out_f32 = (float*)0; p0.out_bs = 0L;
    }
    if (has1) {
      int t = s - 1;
      p1.a0 = (const u16*)0; p1.a0_bs = 0L; p1.wtA = (const u16*)0;
      p1.s0 = (t & 1) ? h0b : h0a;            // h0[t], written by launch s-1
      p1.s0_bs = HB; p1.s0_ch = 2;
      p1.s1 = (t == 0) ? zb : ((t & 1) ? h1a : h1b);
      p1.s1_bs = (t == 0) ? 0L : HB; p1.s1_ch = 2;
      p1.wtB = wtB1; p1.bias = b1; p1.c_t = c1_t;
      p1.h_t = (t & 1) ? h1b : h1a;
      p1.out_f32 = out + (size_t)t * 262144; p1.out_bs = (long)NT * 262144;
    }
    int zbase = has0 ? 0 : 1;
    int zn = (has0 && has1) ? 2 : 1;
    conv_step<<<dim3(32, 8, zn), 512, 0, stream>>>(p0, p1, zbase, zb);
  }

  h1_final<<<8192, 256, 0, stream>>>(out, out + 33554432);
  c1_final<<<dim3(64, 8), 256, 0, stream>>>(c1_t, out + 35651584);
}

// Round 4
// 914.943 us; speedup vs baseline: 1.2680x; 1.0042x over previous
//
#include <hip/hip_runtime.h>
#include <hip/hip_bf16.h>
#include <math.h>

#define HW 4096
#define NB 8
#define NT 16

typedef unsigned short u16;
typedef __attribute__((ext_vector_type(8))) short bf16x8;
typedef __attribute__((ext_vector_type(4))) float f32x4;

__device__ __forceinline__ float sigmoid_f(float x) {
  return 1.f / (1.f + __expf(-x));
}
__device__ __forceinline__ float tanh_f(float x) {
  float ax = fabsf(x);
  float e = __expf(2.f * ax);
  float t = 1.f - 2.f / (e + 1.f);
  return copysignf(t, x);
}
__device__ __forceinline__ u16 f2b(float v) {
  __hip_bfloat16 h = __float2bfloat16(v);
  return *(u16*)&h;
}

// ---- weight transform: w[256][CIN][3][3] f32 -> wtB[chunk][tap][gate][32ci] bf16
__global__ void transform_wB(const float* __restrict__ w, u16* __restrict__ wtB,
                             int CIN, int cinbase, int nch) {
  int idx = blockIdx.x * 256 + threadIdx.x;
  int total = nch * 9 * 256 * 32;
  if (idx >= total) return;
  int ci32 = idx & 31;
  int rest = idx >> 5;
  int gate = rest & 255;
  rest >>= 8;
  int tap = rest % 9;
  int chunk = rest / 9;
  int cin = cinbase + chunk * 32 + ci32;
  wtB[idx] = f2b(w[((size_t)gate * CIN + cin) * 9 + tap]);
}

// ---- layer0 xin-part weights: wtA[gate][32k] bf16, k = ci*9+tap (ci<3), pad 0
__global__ void transform_wA(const float* __restrict__ w0, u16* __restrict__ wtA) {
  int idx = blockIdx.x * 256 + threadIdx.x;  // 8192
  if (idx >= 8192) return;
  int k = idx & 31, gate = idx >> 5;
  u16 v = 0;
  if (k < 27) {
    int ci = (k >= 18) + (k >= 9);
    int tap = k - ci * 9;
    v = f2b(w0[((size_t)gate * 67 + ci) * 9 + tap]);
  }
  wtA[idx] = v;
}

// ---- attention reduce: per (b,t,c) avg & max over HW ----
__global__ void att_reduce(const float* __restrict__ x, float* __restrict__ avg,
                           float* __restrict__ mx) {
  int btc = blockIdx.x;  // 384
  const float* p = x + (size_t)btc * HW;
  float s = 0.f, m = -INFINITY;
  for (int i = threadIdx.x; i < HW; i += 256) {
    float v = p[i];
    s += v;
    m = fmaxf(m, v);
  }
  #pragma unroll
  for (int off = 32; off; off >>= 1) {
    s += __shfl_down(s, off, 64);
    m = fmaxf(m, __shfl_down(m, off, 64));
  }
  __shared__ float ss[4], sm[4];
  int wid = threadIdx.x >> 6, lane = threadIdx.x & 63;
  if (lane == 0) { ss[wid] = s; sm[wid] = m; }
  __syncthreads();
  if (threadIdx.x == 0) {
    avg[btc] = (ss[0] + ss[1] + ss[2] + ss[3]) * (1.f / 4096.f);
    mx[btc]  = fmaxf(fmaxf(sm[0], sm[1]), fmaxf(sm[2], sm[3]));
  }
}

// ---- attention apply -> xin_t[bt][pix][4ci] bf16 (channel-last, slot3 = 0) ----
__global__ void att_apply(const float* __restrict__ x, const float* __restrict__ avg,
                          const float* __restrict__ mx, const float* __restrict__ w1,
                          const float* __restrict__ w2, u16* __restrict__ xin_t) {
  size_t i = (size_t)blockIdx.x * 256 + threadIdx.x;  // 1,572,864 = (bt, c, pix)
  int pix = (int)(i & 4095);
  int c   = (int)((i >> 12) % 3);
  int bt  = (int)(i / (3 * HW));
  const float* a = avg + bt * 3;
  const float* m = mx + bt * 3;
  float ra = fmaxf(0.f, w1[0] * a[0] + w1[1] * a[1] + w1[2] * a[2]);
  float rm = fmaxf(0.f, w1[0] * m[0] + w1[1] * m[1] + w1[2] * m[2]);
  float sc = sigmoid_f(w2[c] * (ra + rm));
  xin_t[((size_t)bt * HW + pix) * 4 + c] = f2b(x[i] * sc);
}

// ---- per-role parameter set for the fused conv kernel ----
struct RoleP {
  const u16* a0; long a0_bs; const u16* wtA;   // layer0 xin path (a0 null otherwise)
  const u16* s0; long s0_bs; int s0_ch;        // h-style source 0 ([b][ch][4096][32])
  const u16* s1; long s1_bs; int s1_ch;        // h-style source 1
  const u16* wtB; const float* bias;
  float* c_t;                                  // [b][4096][64] f32
  u16* h_t;                                    // [b][2][4096][32] bf16
  float* out_f32; long out_bs;                 // [b][t][hc][4096] f32 (or null)
};

// ---- staging: chunk tile = 4 input rows x 66 sites x 32 ch, granule = 16 B ----
// granule idx g in [0,1088): site = g>>2, sub = g&3; LDS linear at g*8 elems.
// sites 0..263 real (row = site/66, col = site%66 - 1), >=264 = tail pad from zb.
__device__ __forceinline__ void dma_site(const u16* sp, u16* bufn, int idx,
                                         const u16* zb, int r0g) {
  int site = idx >> 2, sub = idx & 3;
  int r = site / 66, cc = site - r * 66;
  int gr = r0g - 1 + r, gc = cc - 1;
  const u16* g = (site < 264 && (unsigned)gr < 64u && (unsigned)gc < 64u)
               ? sp + (size_t)(gr * 64 + gc) * 32 + sub * 8
               : zb;                            // OOB / pad lanes read the zero page
  u16* l = bufn + (size_t)(idx & ~63) * 8;      // wave-uniform LDS base; HW adds lane*16
  __builtin_amdgcn_global_load_lds(
      (const __attribute__((address_space(1))) unsigned int*)g,
      (__attribute__((address_space(3))) unsigned int*)l, 16, 0, 0);
}

__device__ __forceinline__ void dma_chunk(const u16* sp, u16* bufn, const u16* zb,
                                          int r0g, int tid) {
  #pragma unroll
  for (int it = 0; it < 4; ++it) dma_site(sp, bufn, it * 256 + tid, zb, r0g);
  if (tid < 64) dma_site(sp, bufn, 1024 + tid, zb, r0g);   // full-wave tail (pads to 1088)
}

#define BQ_LOAD(S, BASE, TP)                                              \
  { _Pragma("unroll")                                                     \
    for (int _g = 0; _g < 4; ++_g)                                        \
      bq[S][_g] = *(const bf16x8*)((BASE) + (TP) * 8192 + _g * 2048); }

// one 9-tap chunk; PAR = global tap parity at chunk start (ring-2, distance-1)
// wave tile: mt 0..7 (128 px = 2 rows), gt 0..3 (64 gates) -> 32 MFMA/tap
// abase = n*32 + q*8
template <int PAR>
__device__ __forceinline__ void chunk_compute(const u16* bufc, const u16* bpc,
                                              const u16* bpn, bool more,
                                              bf16x8 (&bq)[2][4], f32x4 (&acc)[8][4],
                                              int abase) {
  #pragma unroll
  for (int tap = 0; tap < 9; ++tap) {
    if (tap < 8) { BQ_LOAD((tap + 1 + PAR) & 1, bpc, tap + 1) }
    else if (more) { BQ_LOAD((1 + PAR) & 1, bpn, 0) }
    const int dy = tap / 3, dx = tap - dy * 3;
    bf16x8 av[8];
    #pragma unroll
    for (int mt = 0; mt < 8; ++mt)
      av[mt] = *(const bf16x8*)(bufc + abase + ((mt >> 2) + dy) * 2112 + dx * 32 + (mt & 3) * 512);
    #pragma unroll
    for (int mt = 0; mt < 8; ++mt)
      #pragma unroll
      for (int gt = 0; gt < 4; ++gt)
        acc[mt][gt] = __builtin_amdgcn_mfma_f32_16x16x32_bf16(
            av[mt], bq[(tap + PAR) & 1][gt], acc[mt][gt], 0, 0, 0);
  }
}

#define SP_SET(CG)                                                           \
  sp = ((CG) < P.s0_ch)                                                      \
     ? P.s0 + (size_t)b * P.s0_bs + (size_t)(CG) * 131072                    \
     : P.s1 + (size_t)b * P.s1_bs + (size_t)((CG) - P.s0_ch) * 131072;

// ---- fused dual-role implicit-GEMM conv + LSTM pointwise, 2 rows / block ----
// grid (32 row-pairs, 8 batch, nz); role = blockIdx.z + zbase.
// 4 waves (256 thr): wave w = gate-column gc; per wave mt=8 (all 128 px) x gt=4.
// Per-MFMA B traffic halved vs mt=4 (1024/mt B) -> relieves per-CU TCP path.
__global__ __launch_bounds__(256, 2) void conv_step(
    RoleP r0p, RoleP r1p, int zbase, const u16* __restrict__ zb)
{
  __shared__ __align__(16) u16 smem[2][8704];   // 2 x 17,408 B (8448 used + tail pad)
  __shared__ __align__(16) u16 xtile[4096];     // layer0 xin im2col tile (2 rows)
  const RoleP P = (blockIdx.z + zbase) ? r1p : r0p;
  const int r0g = blockIdx.x * 2, b = blockIdx.y;
  const int tid = threadIdx.x;
  const int gc = tid >> 6, lane = tid & 63;
  const int n = lane & 15, q = lane >> 4;
  const int abase = n * 32 + q * 8;
  const int ntot = P.s0_ch + P.s1_ch;           // 2 (layer0) or 4 (layer1), always even

  f32x4 acc[8][4];
  #pragma unroll
  for (int mt = 0; mt < 8; ++mt)
    #pragma unroll
    for (int gt = 0; gt < 4; ++gt)
      acc[mt][gt] = (f32x4){0.f, 0.f, 0.f, 0.f};

  const u16* bp0 = P.wtB + (size_t)(gc * 16 + n) * 32 + q * 8;
  bf16x8 bq[2][4];
  const u16* sp;

  // ---- prologue: chunk-0 DMA + B tap-0, overlap with layer-0 xin staging ----
  SP_SET(0);
  dma_chunk(sp, &smem[0][0], zb, r0g, tid);
  BQ_LOAD(0, bp0, 0)
  if (P.a0) {
    const u16* ap = P.a0 + (size_t)b * P.a0_bs;
    for (int idx = tid; idx < 4096; idx += 256) {
      int row = idx >> 11, rest = idx & 2047;
      int k = rest & 31, px = rest >> 5;
      u16 v = 0;
      if (k < 27) {
        int ci = (k >= 18) + (k >= 9);
        int tap = k - ci * 9;
        int dy = (tap >= 6) ? 2 : (tap >= 3 ? 1 : 0);
        int dx = tap - dy * 3;
        int gr = r0g + row - 1 + dy, gcl = px - 1 + dx;
        if ((unsigned)gr < 64u && (unsigned)gcl < 64u)
          v = ap[((size_t)(gr * 64 + gcl)) * 4 + ci];
      }
      xtile[idx] = v;
    }
  }
  __syncthreads();   // drains DMA (vmcnt0) + xtile writes
  if (P.a0) {
    bf16x8 bxa[4], axv[8];
    #pragma unroll
    for (int gt = 0; gt < 4; ++gt)
      bxa[gt] = *(const bf16x8*)(P.wtA + ((gc + 4 * gt) * 16 + n) * 32 + q * 8);
    #pragma unroll
    for (int mt = 0; mt < 8; ++mt)
      axv[mt] = *(const bf16x8*)(xtile + (mt >> 2) * 2048 + ((mt & 3) * 16 + n) * 32 + q * 8);
    #pragma unroll
    for (int mt = 0; mt < 8; ++mt)
      #pragma unroll
      for (int gt = 0; gt < 4; ++gt)
        acc[mt][gt] = __builtin_amdgcn_mfma_f32_16x16x32_bf16(axv[mt], bxa[gt], acc[mt][gt], 0, 0, 0);
  }

  // ---- main chunk loop, unrolled x2 (compile-time ring parity) ----
  int cur = 0;
  for (int cg = 0; cg < ntot; cg += 2) {
    {   // even-parity chunk: cg (cg+1 < ntot always since ntot even)
      SP_SET(cg + 1);
      dma_chunk(sp, &smem[cur ^ 1][0], zb, r0g, tid);
      chunk_compute<0>(&smem[cur][0], bp0 + (size_t)cg * 73728,
                       bp0 + (size_t)(cg + 1) * 73728, true, bq, acc, abase);
      __syncthreads();
      cur ^= 1;
    }
    {   // odd-parity chunk: cg+1
      bool more = (cg + 2 < ntot);
      if (more) {
        SP_SET(cg + 2);
        dma_chunk(sp, &smem[cur ^ 1][0], zb, r0g, tid);
      }
      chunk_compute<1>(&smem[cur][0], bp0 + (size_t)(cg + 1) * 73728,
                       bp0 + (size_t)(cg + 2) * 73728, more, bq, acc, abase);
      __syncthreads();
      cur ^= 1;
    }
  }

  // ---- LSTM pointwise epilogue (lane-local: hc = 16*gc+n; gt = i,f,o,g) ----
  const int hc = gc * 16 + n;
  const float bi = P.bias[hc], bfv = P.bias[64 + hc], bo = P.bias[128 + hc], bg = P.bias[192 + hc];
  float* cB = P.c_t + ((size_t)b * HW + r0g * 64) * 64 + hc;
  u16*   hB = P.h_t + (size_t)b * 262144 + (size_t)(hc >> 5) * 131072
            + (size_t)(r0g * 64) * 32 + (hc & 31);
  float* tbuf = (float*)&smem[0][0];            // 128 px x 65 floats (33,280 B)
  #pragma unroll
  for (int mt = 0; mt < 8; ++mt) {
    #pragma unroll
    for (int reg = 0; reg < 4; ++reg) {
      int px = mt * 16 + q * 4 + reg;           // 0..127 over both rows
      float xi = acc[mt][0][reg] + bi;
      float xf = acc[mt][1][reg] + bfv;
      float xo = acc[mt][2][reg] + bo;
      float xg = acc[mt][3][reg] + bg;
      float ii = sigmoid_f(xi), ff = sigmoid_f(xf), oo = sigmoid_f(xo), gg = tanh_f(xg);
      float cold = cB[(size_t)px * 64];
      float cnew = ff * cold + ii * gg;
      float hnew = oo * tanh_f(cnew);
      cB[(size_t)px * 64] = cnew;
      hB[(size_t)px * 32] = f2b(hnew);
      if (P.out_f32) tbuf[px * 65 + hc] = hnew;
    }
  }
  if (P.out_f32) {   // coalesced out write via LDS transpose (both rows)
    __syncthreads();
    int hc2 = tid >> 2, qq = tid & 3;
    #pragma unroll
    for (int rw = 0; rw < 2; ++rw) {
      float* orow = P.out_f32 + (size_t)b * P.out_bs + (size_t)hc2 * HW + (r0g + rw) * 64;
      #pragma unroll
      for (int j = 0; j < 4; ++j) {
        int p0x = qq * 4 + j * 16;
        float4 v = make_float4(tbuf[(rw * 64 + p0x + 0) * 65 + hc2],
                               tbuf[(rw * 64 + p0x + 1) * 65 + hc2],
                               tbuf[(rw * 64 + p0x + 2) * 65 + hc2],
                               tbuf[(rw * 64 + p0x + 3) * 65 + hc2]);
        *(float4*)(orow + p0x) = v;
      }
    }
  }
}

// ---- h1 final state: flat copy of out1[:, T-1] ----
__global__ void h1_final(const float* __restrict__ out1, float* __restrict__ dst) {
  size_t i = (size_t)blockIdx.x * 256 + threadIdx.x;  // 2,097,152
  size_t b = i >> 18, rem = i & 262143;
  dst[i] = out1[(b * NT + (NT - 1)) * 262144 + rem];
}

// ---- c1 final state: transpose [b][pix][hc] f32 -> [b][hc][pix] f32 ----
__global__ void c1_final(const float* __restrict__ c_t, float* __restrict__ dst) {
  __shared__ float t[64][65];
  int pb = blockIdx.x, b = blockIdx.y;
  int tx = threadIdx.x & 63, ty = threadIdx.x >> 6;
  for (int i = 0; i < 16; ++i) {
    int p = i * 4 + ty;
    t[p][tx] = c_t[((size_t)b * HW + pb * 64 + p) * 64 + tx];
  }
  __syncthreads();
  for (int i = 0; i < 16; ++i) {
    int hcv = i * 4 + ty;
    dst[(size_t)b * 262144 + (size_t)hcv * HW + pb * 64 + tx] = t[tx][hcv];
  }
}

extern "C" void kernel_launch(void* const* d_in, const int* in_sizes, int n_in,
                              void* d_out, int out_size, void* d_ws, size_t ws_size,
                              hipStream_t stream) {
  const float* x      = (const float*)d_in[0];
  const float* att_w1 = (const float*)d_in[1];
  const float* att_w2 = (const float*)d_in[2];
  const float* w0     = (const float*)d_in[3];
  const float* b0     = (const float*)d_in[4];
  const float* w1     = (const float*)d_in[5];
  const float* b1     = (const float*)d_in[6];
  float* out = (float*)d_out;
  char* ws = (char*)d_ws;

  // workspace layout (byte offsets, all 16B-aligned)
  u16*   xin_t = (u16*)(ws + 0);             // [8][16][4096][4] bf16, 4,194,304 B
  u16*   h0a   = (u16*)(ws + 4194304);       // [8][2][4096][32] bf16
  u16*   h0b   = (u16*)(ws + 8388608);
  u16*   h1a   = (u16*)(ws + 12582912);
  u16*   h1b   = (u16*)(ws + 16777216);
  u16*   zb    = (u16*)(ws + 20971520);      // 262,144 bf16 zeros (bstride 0)
  u16*   wtA0  = (u16*)(ws + 21495808);      // [256][32] bf16
  u16*   wtB0  = (u16*)(ws + 21512192);      // [2][9][256][32] bf16
  u16*   wtB1  = (u16*)(ws + 21807104);      // [4][9][256][32] bf16
  float* c0_t  = (float*)(ws + 22396928);    // [8][4096][64] f32
  float* c1_t  = (float*)(ws + 30785536);
  float* avg   = (float*)(ws + 39174144);    // 384
  float* mxb   = (float*)(ws + 39175680);    // 384
  if (ws_size < 39177216u) return;

  hipMemsetAsync(xin_t, 0, 4194304, stream);       // zeros slot ci=3
  hipMemsetAsync(zb, 0, 524288, stream);
  hipMemsetAsync(c0_t, 0, 8388608, stream);
  hipMemsetAsync(c1_t, 0, 8388608, stream);

  transform_wA<<<32, 256, 0, stream>>>(w0, wtA0);
  transform_wB<<<576, 256, 0, stream>>>(w0, wtB0, 67, 3, 2);
  transform_wB<<<1152, 256, 0, stream>>>(w1, wtB1, 128, 0, 4);
  att_reduce<<<NB * NT * 3, 256, 0, stream>>>(x, avg, mxb);
  att_apply<<<1572864 / 256, 256, 0, stream>>>(x, avg, mxb, att_w1, att_w2, xin_t);

  const long HB = 262144;   // h/c per-batch stride (elems)

  // fused schedule: launch s runs layer0[t=s] (role 0) and layer1[t=s-1] (role 1)
  for (int s = 0; s <= NT; ++s) {
    bool has0 = (s < NT), has1 = (s > 0);
    RoleP p0 = {}, p1 = {};
    if (has0) {
      int t = s;
      p0.a0 = xin_t + (size_t)t * 16384; p0.a0_bs = (long)NT * 16384; p0.wtA = wtA0;
      p0.s0 = (t == 0) ? zb : ((t & 1) ? h0a : h0b);
      p0.s0_bs = (t == 0) ? 0L : HB; p0.s0_ch = 2;
      p0.s1 = zb; p0.s1_bs = 0L; p0.s1_ch = 0;
      p0.wtB = wtB0; p0.bias = b0; p0.c_t = c0_t;
      p0.h_t = (t & 1) ? h0b : h0a;
      p0.out_f32 = (float*)0; p0.out_bs = 0L;
    }
    if (has1) {
      int t = s - 1;
      p1.a0 = (const u16*)0; p1.a0_bs = 0L; p1.wtA = (const u16*)0;
      p1.s0 = (t & 1) ? h0b : h0a;            // h0[t], written by launch s-1
      p1.s0_bs = HB; p1.s0_ch = 2;
      p1.s1 = (t == 0) ? zb : ((t & 1) ? h1a : h1b);
      p1.s1_bs = (t == 0) ? 0L : HB; p1.s1_ch = 2;
      p1.wtB = wtB1; p1.bias = b1; p1.c_t = c1_t;
      p1.h_t = (t & 1) ? h1b : h1a;
      p1.out_f32 = out + (size_t)t * 262144; p1.out_bs = (long)NT * 262144;
    }
    int zbase = has0 ? 0 : 1;
    int zn = (has0 && has1) ? 2 : 1;
    conv_step<<<dim3(32, 8, zn), 256, 0, stream>>>(p0, p1, zbase, zb);
  }

  h1_final<<<8192, 256, 0, stream>>>(out, out + 33554432);
  c1_final<<<dim3(64, 8), 256, 0, stream>>>(c1_t, out + 35651584);
}